// Round 1
// baseline (225.574 us; speedup 1.0000x reference)
//
#include <hip/hip_runtime.h>
#include <math.h>

#define FFT_N   4096
#define LOG_N   12
#define THREADS 512

// One block per row: 4096-point complex FFT in LDS, radix-2 DIT.
// Input is loaded with (even/odd Makhoul permutation) o (bit reversal) so the
// DIT output is in natural order. Epilogue applies DCT[k] = Re(expk[k]*V[k]).
__global__ __launch_bounds__(THREADS) void dct_rows(const float* __restrict__ in,
                                                    const float* __restrict__ expk,
                                                    float* __restrict__ out) {
    __shared__ float2 data[FFT_N];
    __shared__ float2 tw[FFT_N / 2];

    const int row = blockIdx.x;
    const int tid = threadIdx.x;
    const float* __restrict__ src = in + (size_t)row * FFT_N;

    // twiddle table: tw[k] = exp(-2*pi*i*k/N), k < N/2
    for (int k = tid; k < FFT_N / 2; k += THREADS) {
        float ang = -2.0f * (float)M_PI * (float)k / (float)FFT_N;
        float s, c;
        __sincosf(ang, &s, &c);
        tw[k] = make_float2(c, s);
    }

    // load: data[n] = y[bitrev(n)], y = even/odd-permuted row
    for (int n = tid; n < FFT_N; n += THREADS) {
        unsigned br = __brev((unsigned)n) >> (32 - LOG_N);
        int p = (br < (FFT_N / 2)) ? (int)(2u * br) : (int)(8191u - 2u * br);
        data[n] = make_float2(src[p], 0.0f);
    }
    __syncthreads();

    // iterative radix-2 DIT, 12 stages
    for (int logLen = 1; logLen <= LOG_N; ++logLen) {
        const int len   = 1 << logLen;
        const int half  = len >> 1;
        const int shift = LOG_N - logLen;  // twiddle subsample stride (log2)
        for (int b = tid; b < FFT_N / 2; b += THREADS) {
            int j    = b & (half - 1);
            int base = ((b >> (logLen - 1)) << logLen) + j;
            float2 w = tw[j << shift];
            float2 u = data[base];
            float2 v = data[base + half];
            float2 t = make_float2(w.x * v.x - w.y * v.y,
                                   w.x * v.y + w.y * v.x);
            data[base]        = make_float2(u.x + t.x, u.y + t.y);
            data[base + half] = make_float2(u.x - t.x, u.y - t.y);
        }
        __syncthreads();
    }

    // epilogue: out[k] = Re(expk[k] * V[k])
    const float2* __restrict__ e2 = (const float2*)expk;
    float* __restrict__ dst = out + (size_t)row * FFT_N;
    for (int k = tid; k < FFT_N; k += THREADS) {
        float2 w = e2[k];
        float2 V = data[k];
        dst[k] = w.x * V.x - w.y * V.y;
    }
}

// 32x32 LDS-tiled transpose, coalesced on both sides. 4096x4096 f32.
__global__ __launch_bounds__(256) void transpose4k(const float* __restrict__ in,
                                                   float* __restrict__ out) {
    __shared__ float tile[32][33];
    const int x0 = blockIdx.x * 32;
    const int y0 = blockIdx.y * 32;
    const int tx = threadIdx.x & 31;
    const int ty = threadIdx.x >> 5;  // 0..7

    #pragma unroll
    for (int i = 0; i < 32; i += 8)
        tile[ty + i][tx] = in[(size_t)(y0 + ty + i) * FFT_N + (x0 + tx)];
    __syncthreads();
    #pragma unroll
    for (int i = 0; i < 32; i += 8)
        out[(size_t)(x0 + ty + i) * FFT_N + (y0 + tx)] = tile[tx][ty + i];
}

extern "C" void kernel_launch(void* const* d_in, const int* in_sizes, int n_in,
                              void* d_out, int out_size, void* d_ws, size_t ws_size,
                              hipStream_t stream) {
    const float* x     = (const float*)d_in[0];
    const float* expkM = (const float*)d_in[1];
    const float* expkN = (const float*)d_in[2];
    float* out = (float*)d_out;
    float* ws1 = (float*)d_ws;  // 4096*4096 f32 = 67 MB scratch

    // rows pass (along n, twiddle expkN)
    dct_rows<<<FFT_N, THREADS, 0, stream>>>(x, expkN, ws1);
    // transpose into d_out (scratch use; fully overwritten later)
    transpose4k<<<dim3(128, 128), 256, 0, stream>>>(ws1, out);
    // columns pass (along m, twiddle expkM)
    dct_rows<<<FFT_N, THREADS, 0, stream>>>(out, expkM, ws1);
    // transpose back into d_out (final)
    transpose4k<<<dim3(128, 128), 256, 0, stream>>>(ws1, out);
}

// Round 2
// 102.435 us; speedup vs baseline: 2.2021x; 2.2021x over previous
//
#include <hip/hip_runtime.h>
#include <math.h>

#define NFULL 4096   // DCT length per row
#define NH    2048   // half-size complex FFT
#define T     256    // threads per block

__device__ __forceinline__ int pad(int i) { return i + (i >> 3); }

__device__ __forceinline__ float2 cmul(float2 a, float2 b) {
    return make_float2(a.x * b.x - a.y * b.y, a.x * b.y + a.y * b.x);
}

// 8-point DFT, no twiddles: V[k] = sum_r v[r] e^{-2 pi i r k / 8}
__device__ __forceinline__ void dft8(float2 v[8]) {
    const float s = 0.70710678118654752f;
    float2 e0 = v[0], o0 = v[1], e1 = v[2], o1 = v[3];
    float2 e2 = v[4], o2 = v[5], e3 = v[6], o3 = v[7];
    // DFT4 on evens
    float2 t0 = make_float2(e0.x + e2.x, e0.y + e2.y);
    float2 t1 = make_float2(e0.x - e2.x, e0.y - e2.y);
    float2 t2 = make_float2(e1.x + e3.x, e1.y + e3.y);
    float2 t3 = make_float2(e1.x - e3.x, e1.y - e3.y);
    float2 E0 = make_float2(t0.x + t2.x, t0.y + t2.y);
    float2 E2 = make_float2(t0.x - t2.x, t0.y - t2.y);
    float2 E1 = make_float2(t1.x + t3.y, t1.y - t3.x);  // t1 - i t3
    float2 E3 = make_float2(t1.x - t3.y, t1.y + t3.x);  // t1 + i t3
    // DFT4 on odds
    float2 u0 = make_float2(o0.x + o2.x, o0.y + o2.y);
    float2 u1 = make_float2(o0.x - o2.x, o0.y - o2.y);
    float2 u2 = make_float2(o1.x + o3.x, o1.y + o3.y);
    float2 u3 = make_float2(o1.x - o3.x, o1.y - o3.y);
    float2 O0 = make_float2(u0.x + u2.x, u0.y + u2.y);
    float2 O2 = make_float2(u0.x - u2.x, u0.y - u2.y);
    float2 O1 = make_float2(u1.x + u3.y, u1.y - u3.x);
    float2 O3 = make_float2(u1.x - u3.y, u1.y + u3.x);
    // twiddle odd outputs: O1 *= e^{-i pi/4}, O2 *= -i, O3 *= e^{-3i pi/4}
    O1 = make_float2(s * (O1.x + O1.y), s * (O1.y - O1.x));
    O2 = make_float2(O2.y, -O2.x);
    O3 = make_float2(s * (O3.y - O3.x), s * (-O3.x - O3.y));
    v[0] = make_float2(E0.x + O0.x, E0.y + O0.y);
    v[4] = make_float2(E0.x - O0.x, E0.y - O0.y);
    v[1] = make_float2(E1.x + O1.x, E1.y + O1.y);
    v[5] = make_float2(E1.x - O1.x, E1.y - O1.y);
    v[2] = make_float2(E2.x + O2.x, E2.y + O2.y);
    v[6] = make_float2(E2.x - O2.x, E2.y - O2.y);
    v[3] = make_float2(E3.x + O3.x, E3.y + O3.y);
    v[7] = make_float2(E3.x - O3.x, E3.y - O3.y);
}

__device__ __forceinline__ void dft4(float2 v[4]) {
    float2 t0 = make_float2(v[0].x + v[2].x, v[0].y + v[2].y);
    float2 t1 = make_float2(v[0].x - v[2].x, v[0].y - v[2].y);
    float2 t2 = make_float2(v[1].x + v[3].x, v[1].y + v[3].y);
    float2 t3 = make_float2(v[1].x - v[3].x, v[1].y - v[3].y);
    v[0] = make_float2(t0.x + t2.x, t0.y + t2.y);
    v[2] = make_float2(t0.x - t2.x, t0.y - t2.y);
    v[1] = make_float2(t1.x + t3.y, t1.y - t3.x);
    v[3] = make_float2(t1.x - t3.y, t1.y + t3.x);
}

// Per row: DCT-II via Makhoul permutation + real-packed half-size Stockham FFT.
// z[n] = y[2n] + i y[2n+1] where y = even/odd permuted row; Z = FFT_2048(z);
// untangle to Y = FFT_4096(y) on k=0..2047; out[k] = Re(w[k] Y[k]),
// out[N-k] = Re(w[N-k] conj(Y[k])).
__global__ __launch_bounds__(T) void dct_rows_rfft(const float* __restrict__ in,
                                                   const float* __restrict__ expk,
                                                   float* __restrict__ out) {
    __shared__ float2 A[NH + (NH >> 3)];
    __shared__ float2 B[NH + (NH >> 3)];
    const int row = blockIdx.x;
    const int t = threadIdx.x;
    const float4* __restrict__ src4 = (const float4*)(in + (size_t)row * NFULL);

    // load + permute + pack: each input float4 (x[4c..4c+3]) yields
    // z[c] = (x[4c], x[4c+2]) and z[2047-c] = (x[4c+3], x[4c+1])
    #pragma unroll
    for (int i = 0; i < 4; ++i) {
        int c = t + T * i;
        float4 f = src4[c];
        A[pad(c)]        = make_float2(f.x, f.z);
        A[pad(2047 - c)] = make_float2(f.w, f.y);
    }
    __syncthreads();

    float2 v[8];
    // stage 1: R=8, Ns=1, A -> B (no twiddles)
    {
        const int j = t;
        #pragma unroll
        for (int r = 0; r < 8; ++r) v[r] = A[pad(j + 256 * r)];
        dft8(v);
        #pragma unroll
        for (int r = 0; r < 8; ++r) B[pad(8 * j + r)] = v[r];
    }
    __syncthreads();
    // stage 2: R=8, Ns=8, B -> A
    {
        const int j = t;
        #pragma unroll
        for (int r = 0; r < 8; ++r) v[r] = B[pad(j + 256 * r)];
        float ang = -2.0f * (float)M_PI * (float)(j & 7) / 64.0f;
        float sn, cs;
        __sincosf(ang, &sn, &cs);
        float2 w1 = make_float2(cs, sn), w = w1;
        v[1] = cmul(v[1], w);
        #pragma unroll
        for (int r = 2; r < 8; ++r) { w = cmul(w, w1); v[r] = cmul(v[r], w); }
        dft8(v);
        const int d = ((j >> 3) << 6) + (j & 7);
        #pragma unroll
        for (int r = 0; r < 8; ++r) A[pad(d + 8 * r)] = v[r];
    }
    __syncthreads();
    // stage 3: R=8, Ns=64, A -> B
    {
        const int j = t;
        #pragma unroll
        for (int r = 0; r < 8; ++r) v[r] = A[pad(j + 256 * r)];
        float ang = -2.0f * (float)M_PI * (float)(j & 63) / 512.0f;
        float sn, cs;
        __sincosf(ang, &sn, &cs);
        float2 w1 = make_float2(cs, sn), w = w1;
        v[1] = cmul(v[1], w);
        #pragma unroll
        for (int r = 2; r < 8; ++r) { w = cmul(w, w1); v[r] = cmul(v[r], w); }
        dft8(v);
        const int d = ((j >> 6) << 9) + (j & 63);
        #pragma unroll
        for (int r = 0; r < 8; ++r) B[pad(d + 64 * r)] = v[r];
    }
    __syncthreads();
    // stage 4: R=4, Ns=512, B -> A (two butterflies per thread)
    #pragma unroll
    for (int h = 0; h < 2; ++h) {
        const int j = t + 256 * h;
        float2 u[4];
        #pragma unroll
        for (int r = 0; r < 4; ++r) u[r] = B[pad(j + 512 * r)];
        float ang = -2.0f * (float)M_PI * (float)j / 2048.0f;
        float sn, cs;
        __sincosf(ang, &sn, &cs);
        float2 w1 = make_float2(cs, sn);
        u[1] = cmul(u[1], w1);
        float2 w2 = cmul(w1, w1);
        u[2] = cmul(u[2], w2);
        u[3] = cmul(u[3], cmul(w2, w1));
        dft4(u);
        #pragma unroll
        for (int r = 0; r < 4; ++r) A[pad(j + 512 * r)] = u[r];
    }
    __syncthreads();

    // epilogue: untangle rfft + DCT twiddle, write natural order
    const float2* __restrict__ ek = (const float2*)expk;
    float* __restrict__ dst = out + (size_t)row * NFULL;
    #pragma unroll
    for (int i = 0; i < 8; ++i) {
        const int k = t + T * i;
        if (k == 0) {
            float2 z0 = A[pad(0)];
            dst[0]    = ek[0].x * (z0.x + z0.y);     // Y[0]   real
            dst[NH]   = ek[NH].x * (z0.x - z0.y);    // Y[2048] real
        } else {
            float2 Zk = A[pad(k)];
            float2 Zr = A[pad(NH - k)];
            float2 E = make_float2(0.5f * (Zk.x + Zr.x), 0.5f * (Zk.y - Zr.y));
            float2 O = make_float2(0.5f * (Zk.y + Zr.y), 0.5f * (Zr.x - Zk.x));
            float2 wk = ek[k];
            float2 w2 = cmul(wk, wk);
            float2 uu = cmul(w2, w2);                 // e^{-i pi k / 2048}
            float2 Y = make_float2(E.x + uu.x * O.x - uu.y * O.y,
                                   E.y + uu.x * O.y + uu.y * O.x);
            dst[k] = wk.x * Y.x - wk.y * Y.y;
            float2 wn = ek[NFULL - k];
            dst[NFULL - k] = wn.x * Y.x + wn.y * Y.y; // Re(wn * conj(Y))
        }
    }
}

// 32x32 LDS-tiled transpose, coalesced both sides
__global__ __launch_bounds__(256) void transpose4k(const float* __restrict__ in,
                                                   float* __restrict__ out) {
    __shared__ float tile[32][33];
    const int x0 = blockIdx.x * 32;
    const int y0 = blockIdx.y * 32;
    const int tx = threadIdx.x & 31;
    const int ty = threadIdx.x >> 5;

    #pragma unroll
    for (int i = 0; i < 32; i += 8)
        tile[ty + i][tx] = in[(size_t)(y0 + ty + i) * NFULL + (x0 + tx)];
    __syncthreads();
    #pragma unroll
    for (int i = 0; i < 32; i += 8)
        out[(size_t)(x0 + ty + i) * NFULL + (y0 + tx)] = tile[tx][ty + i];
}

extern "C" void kernel_launch(void* const* d_in, const int* in_sizes, int n_in,
                              void* d_out, int out_size, void* d_ws, size_t ws_size,
                              hipStream_t stream) {
    const float* x     = (const float*)d_in[0];
    const float* expkM = (const float*)d_in[1];
    const float* expkN = (const float*)d_in[2];
    float* out = (float*)d_out;
    float* ws1 = (float*)d_ws;

    dct_rows_rfft<<<NFULL, T, 0, stream>>>(x, expkN, ws1);
    transpose4k<<<dim3(128, 128), 256, 0, stream>>>(ws1, out);
    dct_rows_rfft<<<NFULL, T, 0, stream>>>(out, expkM, ws1);
    transpose4k<<<dim3(128, 128), 256, 0, stream>>>(ws1, out);
}